// Round 7
// baseline (718.424 us; speedup 1.0000x reference)
//
#include <hip/hip_runtime.h>
#include <hip/hip_fp16.h>
#include <math.h>

#define HID 32
#define BS 256

// ---- bucketed counting-sort parameters (node sort, dst-keyed) ----
#define NPB 4096          // nodes per bucket (dst range per bucket)
#define NBK_MAX 1024      // LDS sizing cap for bucket count
#define EBT 8192          // items per scatter tile
#define CAP 11776         // per-bucket LDS srt capacity

// ---- edge-inverse bucketing (oec accumulation) ----
#define NPB_E 1024        // edges per bucket (key range per bucket)

// ---- packed half2 helpers (pure clang vector ops -> v_pk_* / v_dot2) ----
typedef _Float16 h2v __attribute__((ext_vector_type(2)));

__device__ __forceinline__ h2v u2h(uint u) { return __builtin_bit_cast(h2v, u); }
__device__ __forceinline__ uint h2u(h2v h) { return __builtin_bit_cast(uint, h); }
__device__ __forceinline__ uint pack2(float a, float b) {
  h2v r; r.x = (_Float16)a; r.y = (_Float16)b; return h2u(r);
}
// z += dot(half2 a, half2 b) with f32 accumulate (v_dot2_f32_f16)
__device__ __forceinline__ float dot2acc(uint a, uint b, float c) {
#if __has_builtin(__builtin_amdgcn_fdot2)
  return __builtin_amdgcn_fdot2(u2h(a), u2h(b), c, false);
#else
  h2v ah = u2h(a), bh = u2h(b);
  c = fmaf((float)ah.x, (float)bh.x, c);
  return fmaf((float)ah.y, (float)bh.y, c);
#endif
}
// extract the .w half (dis) of an 8B half4 row
__device__ __forceinline__ float h4w(uint2 g) {
  h2v hi = u2h(g.y); return (float)hi.y;
}

// ---------------- utility ----------------

__global__ void k_zero_i(int* __restrict__ p, int n) {
  int i = blockIdx.x * BS + threadIdx.x;
  if (i < n) p[i] = 0;
}

// ---------------- bucketed sort: pass A — global bucket histogram ----------------

__global__ __launch_bounds__(BS) void k_bhist(const int* __restrict__ ei,
                                              int* __restrict__ gh, int M, int NBK) {
  __shared__ int hist[NBK_MAX];
  for (int b = threadIdx.x; b < NBK; b += BS) hist[b] = 0;
  __syncthreads();
  int e0 = blockIdx.x * EBT;
  int n = min(EBT, M - e0);
  for (int k = threadIdx.x; k < n; k += BS) {
    int d = ei[M + e0 + k];
    atomicAdd(&hist[d / NPB], 1);
  }
  __syncthreads();
  for (int b = threadIdx.x; b < NBK; b += BS)
    if (hist[b]) atomicAdd(&gh[b], hist[b]);
}

// ---------------- pass B — single-block scan of bucket sizes (generic) ----------------

__global__ __launch_bounds__(BS) void k_bscan(const int* __restrict__ gh,
                                              int* __restrict__ gboff,
                                              int* __restrict__ gcur, int NBK) {
  __shared__ int part[BS];
  int C = (NBK + BS - 1) / BS;
  int s = 0;
  for (int k = 0; k < C; ++k) {
    int idx = threadIdx.x * C + k;
    if (idx < NBK) s += gh[idx];
  }
  part[threadIdx.x] = s;
  __syncthreads();
  for (int off = 1; off < BS; off <<= 1) {
    int v = part[threadIdx.x];
    int u = (threadIdx.x >= off) ? part[threadIdx.x - off] : 0;
    __syncthreads();
    part[threadIdx.x] = v + u;
    __syncthreads();
  }
  int run = (threadIdx.x > 0) ? part[threadIdx.x - 1] : 0;
  for (int k = 0; k < C; ++k) {
    int idx = threadIdx.x * C + k;
    if (idx < NBK) {
      gboff[idx] = run;
      gcur[idx] = run;
      run += gh[idx];
    }
  }
  if (threadIdx.x == BS - 1) gboff[NBK] = run;  // == total items
}

// ---------------- pass C — tiled scatter of (src,dst) pairs into bucket runs ----------------

__global__ __launch_bounds__(BS) void k_bscatter(const int* __restrict__ ei,
                                                 int* __restrict__ gcur,
                                                 int2* __restrict__ P, int M, int NBK) {
  __shared__ int hist[NBK_MAX];
  __shared__ int excl[NBK_MAX];
  __shared__ int curs[NBK_MAX];
  __shared__ int base[NBK_MAX];
  __shared__ int part[BS];
  for (int b = threadIdx.x; b < NBK; b += BS) hist[b] = 0;
  __syncthreads();
  int e0 = blockIdx.x * EBT;
  int n = min(EBT, M - e0);
  for (int k = threadIdx.x; k < n; k += BS) {
    int d = ei[M + e0 + k];
    atomicAdd(&hist[d / NPB], 1);
  }
  __syncthreads();
  int C = (NBK + BS - 1) / BS;
  int s = 0;
  for (int k = 0; k < C; ++k) {
    int idx = threadIdx.x * C + k;
    if (idx < NBK) s += hist[idx];
  }
  part[threadIdx.x] = s;
  __syncthreads();
  for (int off = 1; off < BS; off <<= 1) {
    int v = part[threadIdx.x];
    int u = (threadIdx.x >= off) ? part[threadIdx.x - off] : 0;
    __syncthreads();
    part[threadIdx.x] = v + u;
    __syncthreads();
  }
  int run = (threadIdx.x > 0) ? part[threadIdx.x - 1] : 0;
  for (int k = 0; k < C; ++k) {
    int idx = threadIdx.x * C + k;
    if (idx < NBK) {
      excl[idx] = run;
      curs[idx] = run;
      run += hist[idx];
    }
  }
  __syncthreads();
  for (int b = threadIdx.x; b < NBK; b += BS)
    base[b] = hist[b] ? atomicAdd(&gcur[b], hist[b]) : 0;
  __syncthreads();
  for (int k = threadIdx.x; k < n; k += BS) {
    int sidx = ei[e0 + k];
    int d = ei[M + e0 + k];
    int b = d / NPB;
    int pos = atomicAdd(&curs[b], 1);
    int gpos = base[b] + (pos - excl[b]);
    P[gpos] = make_int2(sidx, d);
  }
}

// ---------------- pass D — per-bucket LDS counting sort -> row_ptr + srt ----------------

__global__ __launch_bounds__(BS) void k_bfinal(const int2* __restrict__ P,
                                               const int* __restrict__ gboff,
                                               int* __restrict__ row_ptr,
                                               int* __restrict__ srt, int T, int M,
                                               int NBK) {
  __shared__ int cnt[NPB];
  __shared__ int lsrt[CAP];
  __shared__ int part[BS];
  int b = blockIdx.x;
  int d0 = b * NPB;
  int nodesHere = min(NPB, T - d0);
  int p0 = gboff[b], p1 = gboff[b + 1];
  int nE = p1 - p0;
  for (int j = threadIdx.x; j < NPB; j += BS) cnt[j] = 0;
  __syncthreads();
  for (int j = threadIdx.x; j < nE; j += BS) {
    int2 p = P[p0 + j];
    atomicAdd(&cnt[p.y - d0], 1);
  }
  __syncthreads();
  const int CN = NPB / BS;  // 16
  int s = 0;
#pragma unroll
  for (int k = 0; k < CN; ++k) s += cnt[threadIdx.x * CN + k];
  part[threadIdx.x] = s;
  __syncthreads();
  for (int off = 1; off < BS; off <<= 1) {
    int v = part[threadIdx.x];
    int u = (threadIdx.x >= off) ? part[threadIdx.x - off] : 0;
    __syncthreads();
    part[threadIdx.x] = v + u;
    __syncthreads();
  }
  int run = (threadIdx.x > 0) ? part[threadIdx.x - 1] : 0;
#pragma unroll
  for (int k = 0; k < CN; ++k) {
    int idx = threadIdx.x * CN + k;
    int c = cnt[idx];
    cnt[idx] = run;
    if (idx < nodesHere) row_ptr[d0 + idx] = p0 + run;
    run += c;
  }
  if (b == NBK - 1 && threadIdx.x == 0) row_ptr[T] = M;
  __syncthreads();
  if (nE <= CAP) {
    for (int j = threadIdx.x; j < nE; j += BS) {
      int2 p = P[p0 + j];
      int pos = atomicAdd(&cnt[p.y - d0], 1);
      lsrt[pos] = p.x;
    }
    __syncthreads();
    for (int j = threadIdx.x; j < nE; j += BS) srt[p0 + j] = lsrt[j];
  } else {
    for (int j = threadIdx.x; j < nE; j += BS) {
      int2 p = P[p0 + j];
      int pos = atomicAdd(&cnt[p.y - d0], 1);
      srt[p0 + pos] = p.x;
    }
  }
}

// ---------------- edge-inverse bucketing for oec (pairs: key=edge, payload=j) ----------------
// j in [0,3T): slot = j/T (which corr array), triplet = j%T. dd is laid out as
// dd[j] so k_oecsum never needs the decomposition.

__global__ __launch_bounds__(BS) void k_ehist(const int* __restrict__ c12,
                                              const int* __restrict__ c13,
                                              const int* __restrict__ c23,
                                              int* __restrict__ gh, int T, int NBK) {
  __shared__ int hist[NBK_MAX];
  for (int b = threadIdx.x; b < NBK; b += BS) hist[b] = 0;
  __syncthreads();
  int N3 = 3 * T;
  int j0 = blockIdx.x * EBT;
  int n = min(EBT, N3 - j0);
  for (int k = threadIdx.x; k < n; k += BS) {
    int j = j0 + k;
    int key = (j < T) ? c12[j] : ((j < 2 * T) ? c13[j - T] : c23[j - 2 * T]);
    atomicAdd(&hist[key / NPB_E], 1);
  }
  __syncthreads();
  for (int b = threadIdx.x; b < NBK; b += BS)
    if (hist[b]) atomicAdd(&gh[b], hist[b]);
}

__global__ __launch_bounds__(BS) void k_escatter(const int* __restrict__ c12,
                                                 const int* __restrict__ c13,
                                                 const int* __restrict__ c23,
                                                 int* __restrict__ gcur,
                                                 int2* __restrict__ PE, int T, int NBK) {
  __shared__ int hist[NBK_MAX];
  __shared__ int excl[NBK_MAX];
  __shared__ int curs[NBK_MAX];
  __shared__ int base[NBK_MAX];
  __shared__ int part[BS];
  for (int b = threadIdx.x; b < NBK; b += BS) hist[b] = 0;
  __syncthreads();
  int N3 = 3 * T;
  int j0 = blockIdx.x * EBT;
  int n = min(EBT, N3 - j0);
  for (int k = threadIdx.x; k < n; k += BS) {
    int j = j0 + k;
    int key = (j < T) ? c12[j] : ((j < 2 * T) ? c13[j - T] : c23[j - 2 * T]);
    atomicAdd(&hist[key / NPB_E], 1);
  }
  __syncthreads();
  int C = (NBK + BS - 1) / BS;
  int s = 0;
  for (int k = 0; k < C; ++k) {
    int idx = threadIdx.x * C + k;
    if (idx < NBK) s += hist[idx];
  }
  part[threadIdx.x] = s;
  __syncthreads();
  for (int off = 1; off < BS; off <<= 1) {
    int v = part[threadIdx.x];
    int u = (threadIdx.x >= off) ? part[threadIdx.x - off] : 0;
    __syncthreads();
    part[threadIdx.x] = v + u;
    __syncthreads();
  }
  int run = (threadIdx.x > 0) ? part[threadIdx.x - 1] : 0;
  for (int k = 0; k < C; ++k) {
    int idx = threadIdx.x * C + k;
    if (idx < NBK) {
      excl[idx] = run;
      curs[idx] = run;
      run += hist[idx];
    }
  }
  __syncthreads();
  for (int b = threadIdx.x; b < NBK; b += BS)
    base[b] = hist[b] ? atomicAdd(&gcur[b], hist[b]) : 0;
  __syncthreads();
  for (int k = threadIdx.x; k < n; k += BS) {
    int j = j0 + k;
    int key = (j < T) ? c12[j] : ((j < 2 * T) ? c13[j - T] : c23[j - 2 * T]);
    int b = key / NPB_E;
    int pos = atomicAdd(&curs[b], 1);
    int gpos = base[b] + (pos - excl[b]);
    PE[gpos] = make_int2(key, j);
  }
}

// per-bucket reduce: oec[e] += sum of dd[payload] over contributors of e.
// Random 4B READS (L3-resident 24MB dd) in a dependence-free throughput kernel,
// replacing 6M random atomic RMWs in the hot kernel.
__global__ __launch_bounds__(BS) void k_oecsum(const int2* __restrict__ PE,
                                               const int* __restrict__ gboff,
                                               const float* __restrict__ dd,
                                               float* __restrict__ oec, int E) {
  __shared__ float acc[NPB_E];
  int b = blockIdx.x;
  int e0 = b * NPB_E;
  int p0 = gboff[b], p1 = gboff[b + 1];
  int n = p1 - p0;
  for (int j = threadIdx.x; j < NPB_E; j += BS) acc[j] = 0.0f;
  __syncthreads();
  int k = threadIdx.x;
  for (; k + 3 * BS < n; k += 4 * BS) {
    int2 q0 = PE[p0 + k];
    int2 q1 = PE[p0 + k + BS];
    int2 q2 = PE[p0 + k + 2 * BS];
    int2 q3 = PE[p0 + k + 3 * BS];
    float v0 = dd[q0.y];
    float v1 = dd[q1.y];
    float v2 = dd[q2.y];
    float v3 = dd[q3.y];
    atomicAdd(&acc[q0.x - e0], v0);
    atomicAdd(&acc[q1.x - e0], v1);
    atomicAdd(&acc[q2.x - e0], v2);
    atomicAdd(&acc[q3.x - e0], v3);
  }
  for (; k < n; k += BS) {
    int2 q = PE[p0 + k];
    atomicAdd(&acc[q.x - e0], dd[q.y]);
  }
  __syncthreads();
  int lim = min(NPB_E, E - e0);
  for (int j = threadIdx.x; j < lim; j += BS) oec[e0 + j] += acc[j];
}

// ---------------- math kernels ----------------

// msg[e] = ec[e]/cnt[e]; oec[e] = (cnt>0) ? 0 : ec  (one pass over E)
__global__ void k_prep_e(const float* __restrict__ ec, const float* __restrict__ cnt,
                         float* __restrict__ msg, float* __restrict__ oec, int E) {
  int i = blockIdx.x * BS + threadIdx.x;
  if (i >= E) return;
  float c = cnt[i], v = ec[i];
  msg[i] = v / c;
  oec[i] = (c > 0.0f) ? 0.0f : v;
}

// step 1: tri4[i] = (t12+msg, t13+msg, t23+msg, dis_i)  (f32, for self/outputs)
//         trih[i] = same row packed half4 (8B, gather table for layer 1)
__global__ void k_step1pack(const float* __restrict__ msg,
                            const float* __restrict__ t12, const float* __restrict__ t13,
                            const float* __restrict__ t23,
                            const int* __restrict__ c12, const int* __restrict__ c13,
                            const int* __restrict__ c23,
                            const int* __restrict__ row_ptr,
                            float4* __restrict__ tri4, uint2* __restrict__ trih, int T) {
  int i = blockIdx.x * BS + threadIdx.x;
  if (i >= T) return;
  int a = c12[i], b = c13[i], c = c23[i];
  float4 v;
  v.x = t12[i] + msg[a];
  v.y = t13[i] + msg[b];
  v.z = t23[i] + msg[c];
  v.w = rsqrtf((float)(row_ptr[i + 1] - row_ptr[i]) + 1.0f);
  tri4[i] = v;
  uint2 h;
  h.x = pack2(v.x, v.y);
  h.y = pack2(v.z, v.w);
  trih[i] = h;
}

// ---- pack weights to half2 (one-time, trivially cheap) ----
__global__ void k_packw(const float* __restrict__ W1, const float* __restrict__ b1,
                        const float* __restrict__ W2, uint* __restrict__ pkw) {
  int i = blockIdx.x * BS + threadIdx.x;
  if (i < 48) {
    int r = i >> 4, k = i & 15;
    pkw[i] = pack2(W1[r * HID + 2 * k], W1[r * HID + 2 * k + 1]);
  } else if (i < 64) {
    int k = i - 48;
    pkw[i] = pack2(b1[2 * k], b1[2 * k + 1]);
  } else if (i < 576) {
    int idx = i - 64;
    int h2 = idx >> 5, j = idx & 31;
    pkw[i] = pack2(W2[(2 * h2) * HID + j], W2[(2 * h2 + 1) * HID + j]);
  }
}

// accumulate one gathered half4 tri row: (ax,ay,az) += tri.xyz * (tri.w * di)
__device__ __forceinline__ void acc3(uint2 g, float di, float& ax, float& ay, float& az) {
  h2v lo = u2h(g.x), hi = u2h(g.y);
  float w = (float)hi.y * di;
  ax = fmaf((float)lo.x, w, ax);
  ay = fmaf((float)lo.y, w, ay);
  az = fmaf((float)hi.x, w, az);
}

// ---- layer-1 aggregate (pre-W1, linearity) -> G4h = half4(ax,ay,az,di), 8B rows ----
__global__ __launch_bounds__(BS) void k_agg1c(const int* __restrict__ row_ptr,
                                              const int* __restrict__ srt,
                                              const float4* __restrict__ tri4,
                                              const uint2* __restrict__ trih,
                                              uint2* __restrict__ G4h, int T) {
  int i = blockIdx.x * BS + threadIdx.x;
  if (i >= T) return;
  int r0 = row_ptr[i], r1 = row_ptr[i + 1];
  float4 ts = tri4[i];
  float di = ts.w;
  float d2 = di * di;
  float ax = ts.x * d2, ay = ts.y * d2, az = ts.z * d2;
  int e = r0;
  for (; e + 4 <= r1; e += 4) {
    int s0 = srt[e + 0];
    int s1 = srt[e + 1];
    int s2 = srt[e + 2];
    int s3 = srt[e + 3];
    uint2 g0 = trih[s0];
    uint2 g1 = trih[s1];
    uint2 g2 = trih[s2];
    uint2 g3 = trih[s3];
    acc3(g0, di, ax, ay, az);
    acc3(g1, di, ax, ay, az);
    acc3(g2, di, ax, ay, az);
    acc3(g3, di, ax, ay, az);
  }
  for (; e < r1; ++e) {
    uint2 g = trih[srt[e]];
    acc3(g, di, ax, ay, az);
  }
  uint2 o;
  o.x = pack2(ax, ay);
  o.y = pack2(az, di);
  G4h[i] = o;
}

// per-edge packed h1 expand + f32 mix-accumulate from an 8B half4 G row:
// S[2k..] += relu((gx,gy,gz)@W1 + b1)[2k..] * w
__device__ __forceinline__ void edge_h1_accu(uint2 g, float w,
                                             const uint* __restrict__ W1s,
                                             const uint* __restrict__ b1s,
                                             float* S) {
  h2v lo = u2h(g.x), hi = u2h(g.y);
  h2v hx; hx.x = lo.x; hx.y = lo.x;
  h2v hy; hy.x = lo.y; hy.y = lo.y;
  h2v hz; hz.x = hi.x; hz.y = hi.x;
  h2v zero; zero.x = (_Float16)0.f; zero.y = (_Float16)0.f;
#pragma unroll
  for (int k = 0; k < 16; ++k) {
    h2v t = hx * u2h(W1s[k]) + (hy * u2h(W1s[16 + k]) + (hz * u2h(W1s[32 + k]) + u2h(b1s[k])));
    t = __builtin_elementwise_max(t, zero);
    S[2 * k]     = fmaf((float)t.x, w, S[2 * k]);
    S[2 * k + 1] = fmaf((float)t.y, w, S[2 * k + 1]);
  }
}

// fused layer-2 (recompute-h1 from 8B G4h gathers) + packed W2 + head.
// R6 post-mortem: ~310us floor insensitive to VALU/traffic/occupancy/MLP =
// random-transaction-rate floor (~10M scattered trans: 4M gathers + 6M atomic
// RMWs). This round removes the 6M atomics: deltas written as coalesced dd[3T]
// streams; oec accumulated by k_oecsum via the static inverse-CSR (random
// READS in a throughput kernel instead of RMWs here).
__global__ __launch_bounds__(BS) void k_l2head(
    const int* __restrict__ row_ptr, const int* __restrict__ srt,
    const uint2* __restrict__ G4h, const float4* __restrict__ tri4,
    const uint* __restrict__ pkw,
    const float* __restrict__ b2,
    const float* __restrict__ Wout, const float* __restrict__ bout,
    float* __restrict__ o12, float* __restrict__ o13, float* __restrict__ o23,
    float* __restrict__ dd, int T) {
  int i = blockIdx.x * BS + threadIdx.x;
  if (i >= T) return;
  int r0 = row_ptr[i], r1 = row_ptr[i + 1];
  uint2 gs = G4h[i];
  float4 tp = tri4[i];
  float di = tp.w;
  const uint* W1s = pkw;        // 48 u32
  const uint* b1s = pkw + 48;   // 16 u32
  const uint* W2s = pkw + 64;   // 512 u32

  float S[HID];
#pragma unroll
  for (int h = 0; h < HID; ++h) S[h] = 0.0f;

  // self-loop term: h1(G_i) * di^2
  edge_h1_accu(gs, di * di, W1s, b1s, S);

  // edge terms: h1(G_src) * (d_src * d_i); 4/2/1 ladder keeps up to 4 random
  // 8B loads in flight before any h1 math.
  int e = r0;
  for (; e + 4 <= r1; e += 4) {
    int s0 = srt[e + 0];
    int s1 = srt[e + 1];
    int s2 = srt[e + 2];
    int s3 = srt[e + 3];
    uint2 g0 = G4h[s0];
    uint2 g1 = G4h[s1];
    uint2 g2 = G4h[s2];
    uint2 g3 = G4h[s3];
    float w0 = h4w(g0) * di;
    float w1 = h4w(g1) * di;
    float w2 = h4w(g2) * di;
    float w3 = h4w(g3) * di;
    edge_h1_accu(g0, w0, W1s, b1s, S);
    edge_h1_accu(g1, w1, W1s, b1s, S);
    edge_h1_accu(g2, w2, W1s, b1s, S);
    edge_h1_accu(g3, w3, W1s, b1s, S);
  }
  if (e + 2 <= r1) {
    int s0 = srt[e + 0];
    int s1 = srt[e + 1];
    uint2 g0 = G4h[s0];
    uint2 g1 = G4h[s1];
    float w0 = h4w(g0) * di;
    float w1 = h4w(g1) * di;
    edge_h1_accu(g0, w0, W1s, b1s, S);
    edge_h1_accu(g1, w1, W1s, b1s, S);
    e += 2;
  }
  if (e < r1) {
    uint2 g = G4h[srt[e]];
    edge_h1_accu(g, h4w(g) * di, W1s, b1s, S);
  }

  // pack S once into consecutive-h half2 pairs for dot2
  uint sh[16];
#pragma unroll
  for (int k = 0; k < 16; ++k) sh[k] = pack2(S[2 * k], S[2 * k + 1]);

  // z = S @ W2 + b2 via v_dot2_f32_f16 (f32 accumulate); head folded per chunk of 8
  float d0 = bout[0], d1 = bout[1], dd2 = bout[2];
#pragma unroll
  for (int cz = 0; cz < 4; ++cz) {
    float z[8];
#pragma unroll
    for (int j = 0; j < 8; ++j) z[j] = b2[cz * 8 + j];
#pragma unroll
    for (int h2 = 0; h2 < 16; ++h2) {
#pragma unroll
      for (int j = 0; j < 8; ++j)
        z[j] = dot2acc(sh[h2], W2s[h2 * HID + cz * 8 + j], z[j]);
    }
#pragma unroll
    for (int j = 0; j < 8; ++j) {
      float v = fmaxf(z[j], 0.0f);
      int jp = cz * 8 + j;
      d0  = fmaf(v, Wout[jp * 3 + 0], d0);
      d1  = fmaf(v, Wout[jp * 3 + 1], d1);
      dd2 = fmaf(v, Wout[jp * 3 + 2], dd2);
    }
  }

  o12[i] = tp.x - d0;
  o13[i] = tp.y - d1;
  o23[i] = tp.z - dd2;
  // coalesced delta streams, laid out so dd[j] matches contributor id j
  dd[i] = d0;
  dd[T + i] = d1;
  dd[2 * T + i] = dd2;
}

// ---------------- launch ----------------

extern "C" void kernel_launch(void* const* d_in, const int* in_sizes, int n_in,
                              void* d_out, int out_size, void* d_ws, size_t ws_size,
                              hipStream_t stream) {
  const float* ec  = (const float*)d_in[0];
  const float* t12 = (const float*)d_in[1];
  const float* t13 = (const float*)d_in[2];
  const float* t23 = (const float*)d_in[3];
  const int* c12   = (const int*)d_in[4];
  const int* c13   = (const int*)d_in[5];
  const int* c23   = (const int*)d_in[6];
  const float* cnt = (const float*)d_in[7];
  const int* ei    = (const int*)d_in[8];
  const float* W1  = (const float*)d_in[9];
  const float* b1  = (const float*)d_in[10];
  const float* W2  = (const float*)d_in[11];
  const float* b2  = (const float*)d_in[12];
  const float* Wout = (const float*)d_in[13];
  const float* bout = (const float*)d_in[14];

  const int E = in_sizes[0];
  const int T = in_sizes[1];
  const int M = in_sizes[8] / 2;
  const int NBK = (T + NPB - 1) / NPB;        // node buckets
  const int NBK_E = (E + NPB_E - 1) / NPB_E;  // edge buckets (977 for E=1M)

  float* oec = (float*)d_out;
  float* o12 = oec + E;
  float* o13 = o12 + T;
  float* o23 = o13 + T;

  // workspace (~164 MB):
  // tri4 32MB | trih 16 | G4h 16 | PE 48 (int2*3T) | dd 24 (float*3T) | srt 16 |
  // rptr 8 | msg 4 | gh/gboff/gcur | pkw | gh_e/gboff_e/gcur_e
  // P (int2*M = 32MB) aliases tri4 (P dead after k_bfinal; tri4 written in k_step1pack).
  float4* tri4 = (float4*)d_ws;
  uint2*  trih = (uint2*)(tri4 + T);
  uint2*  G4h  = trih + T;
  int2*   PE   = (int2*)(G4h + T);            // 3T pairs
  float*  dd   = (float*)(PE + 3 * (size_t)T);
  int*    srt  = (int*)(dd + 3 * (size_t)T);
  int*    rptr = srt + M;
  float*  msg  = (float*)(rptr + (T + 1));
  int*    gh   = (int*)(msg + E);
  int*    gboff = gh + NBK;
  int*    gcur  = gboff + (NBK + 1);
  uint*   pkw   = (uint*)(gcur + NBK);
  int*    gh_e  = (int*)(pkw + 576);
  int*    gboff_e = gh_e + NBK_E;
  int*    gcur_e  = gboff_e + (NBK_E + 1);
  int2*   P    = (int2*)tri4;  // alias: dead before tri4 written

  auto blocks = [](long n) { return (int)((n + BS - 1) / BS); };
  const int tiles   = (M + EBT - 1) / EBT;
  const int tiles_e = (3 * T + EBT - 1) / EBT;

  // bucketed counting sort by dst -> row_ptr + srt
  k_zero_i<<<blocks(NBK), BS, 0, stream>>>(gh, NBK);
  k_bhist<<<tiles, BS, 0, stream>>>(ei, gh, M, NBK);
  k_bscan<<<1, BS, 0, stream>>>(gh, gboff, gcur, NBK);
  k_bscatter<<<tiles, BS, 0, stream>>>(ei, gcur, P, M, NBK);
  k_bfinal<<<NBK, BS, 0, stream>>>(P, gboff, rptr, srt, T, M, NBK);

  // edge-inverse bucketing of (corr -> contributor) pairs (static, index-only)
  k_zero_i<<<blocks(NBK_E), BS, 0, stream>>>(gh_e, NBK_E);
  k_ehist<<<tiles_e, BS, 0, stream>>>(c12, c13, c23, gh_e, T, NBK_E);
  k_bscan<<<1, BS, 0, stream>>>(gh_e, gboff_e, gcur_e, NBK_E);
  k_escatter<<<tiles_e, BS, 0, stream>>>(c12, c13, c23, gcur_e, PE, T, NBK_E);

  // pack weights (tiny), per-edge prep, step-1 pack (f32 + half4 copies)
  k_packw<<<3, BS, 0, stream>>>(W1, b1, W2, pkw);
  k_prep_e<<<blocks(E), BS, 0, stream>>>(ec, cnt, msg, oec, E);
  k_step1pack<<<blocks(T), BS, 0, stream>>>(msg, t12, t13, t23, c12, c13, c23,
                                            rptr, tri4, trih, T);

  // layer 1 aggregate (pre-W1) -> half4 G rows
  k_agg1c<<<blocks(T), BS, 0, stream>>>(rptr, srt, tri4, trih, G4h, T);

  // layer 2: gather 8B G rows, packed-f16 h1 recompute + dot2 W2 + head
  k_l2head<<<blocks(T), BS, 0, stream>>>(rptr, srt, G4h, tri4, pkw,
                                         b2, Wout, bout,
                                         o12, o13, o23, dd, T);

  // oec accumulation: per-edge-bucket LDS reduce of dd over the inverse-CSR
  k_oecsum<<<NBK_E, BS, 0, stream>>>(PE, gboff_e, dd, oec, E);
}

// Round 8
// 618.266 us; speedup vs baseline: 1.1620x; 1.1620x over previous
//
#include <hip/hip_runtime.h>
#include <hip/hip_fp16.h>
#include <math.h>

#define HID 32
#define BS 256

// ---- bucketed counting-sort parameters (node sort, dst-keyed) ----
#define NPB 4096          // nodes per bucket (dst range per bucket)
#define NBK_MAX 1024      // LDS sizing cap for bucket count
#define EBT 8192          // items per tile
#define CAP 11776         // per-bucket LDS srt capacity

// ---- edge-inverse bucketing (oec accumulation) ----
#define NPB_E 2048        // edges per bucket (key range per bucket)

// ---- packed half2 helpers (pure clang vector ops -> v_pk_* / v_dot2) ----
typedef _Float16 h2v __attribute__((ext_vector_type(2)));

__device__ __forceinline__ h2v u2h(uint u) { return __builtin_bit_cast(h2v, u); }
__device__ __forceinline__ uint h2u(h2v h) { return __builtin_bit_cast(uint, h); }
__device__ __forceinline__ uint pack2(float a, float b) {
  h2v r; r.x = (_Float16)a; r.y = (_Float16)b; return h2u(r);
}
// z += dot(half2 a, half2 b) with f32 accumulate (v_dot2_f32_f16)
__device__ __forceinline__ float dot2acc(uint a, uint b, float c) {
#if __has_builtin(__builtin_amdgcn_fdot2)
  return __builtin_amdgcn_fdot2(u2h(a), u2h(b), c, false);
#else
  h2v ah = u2h(a), bh = u2h(b);
  c = fmaf((float)ah.x, (float)bh.x, c);
  return fmaf((float)ah.y, (float)bh.y, c);
#endif
}
// extract the .w half (dis) of an 8B half4 row
__device__ __forceinline__ float h4w(uint2 g) {
  h2v hi = u2h(g.y); return (float)hi.y;
}

// ---------------- deterministic-tiling bucket machinery ----------------
// R7 post-mortem: infra (sort + edge-inverse) is now the bulk (~400us spread).
// Old scheme read keys twice per scatter (hist phase + placement) and re-derived
// per-tile bases via gcur atomics. New scheme: hist kernels PERSIST per-tile
// histograms thist[t][b]; k_tbase scans tiles per bucket -> tbase[t][b] + totals;
// placement is single-phase with LDS cursors at gboff[b]+tbase[t][b] (no global
// atomics, no key re-read, no per-tile scan).

// node-key histogram: per tile, write thist row (coalesced)
__global__ __launch_bounds__(BS) void k_bhist2(const int* __restrict__ ei,
                                               int* __restrict__ thist, int M, int NBK) {
  __shared__ int hist[NBK_MAX];
  for (int b = threadIdx.x; b < NBK; b += BS) hist[b] = 0;
  __syncthreads();
  int e0 = blockIdx.x * EBT;
  int n = min(EBT, M - e0);
  for (int k = threadIdx.x; k < n; k += BS) {
    int d = ei[M + e0 + k];
    atomicAdd(&hist[d / NPB], 1);
  }
  __syncthreads();
  for (int b = threadIdx.x; b < NBK; b += BS)
    thist[blockIdx.x * NBK + b] = hist[b];
}

// edge-key histogram over contributors j in [0,3T)
__global__ __launch_bounds__(BS) void k_ehist2(const int* __restrict__ c12,
                                               const int* __restrict__ c13,
                                               const int* __restrict__ c23,
                                               int* __restrict__ thist, int T, int NBK) {
  __shared__ int hist[NBK_MAX];
  for (int b = threadIdx.x; b < NBK; b += BS) hist[b] = 0;
  __syncthreads();
  int N3 = 3 * T;
  int j0 = blockIdx.x * EBT;
  int n = min(EBT, N3 - j0);
  for (int k = threadIdx.x; k < n; k += BS) {
    int j = j0 + k;
    int key = (j < T) ? c12[j] : ((j < 2 * T) ? c13[j - T] : c23[j - 2 * T]);
    atomicAdd(&hist[key / NPB_E], 1);
  }
  __syncthreads();
  for (int b = threadIdx.x; b < NBK; b += BS)
    thist[blockIdx.x * NBK + b] = hist[b];
}

// per-bucket exclusive scan over tiles: tbase[t][b], gh[b]=total
__global__ __launch_bounds__(BS) void k_tbase(const int* __restrict__ thist,
                                              int* __restrict__ tbase,
                                              int* __restrict__ gh, int NBK, int NT) {
  __shared__ int part[BS];
  int b = blockIdx.x;
  int C = (NT + BS - 1) / BS;
  int s = 0;
  for (int k = 0; k < C; ++k) {
    int t = threadIdx.x * C + k;
    if (t < NT) s += thist[t * NBK + b];
  }
  part[threadIdx.x] = s;
  __syncthreads();
  for (int off = 1; off < BS; off <<= 1) {
    int v = part[threadIdx.x];
    int u = (threadIdx.x >= off) ? part[threadIdx.x - off] : 0;
    __syncthreads();
    part[threadIdx.x] = v + u;
    __syncthreads();
  }
  int run = (threadIdx.x > 0) ? part[threadIdx.x - 1] : 0;
  for (int k = 0; k < C; ++k) {
    int t = threadIdx.x * C + k;
    if (t < NT) {
      int v = thist[t * NBK + b];
      tbase[t * NBK + b] = run;
      run += v;
    }
  }
  if (threadIdx.x == BS - 1) gh[b] = run;
}

// single-block scan of bucket totals -> gboff (gcur scratch, unused downstream)
__global__ __launch_bounds__(BS) void k_bscan(const int* __restrict__ gh,
                                              int* __restrict__ gboff,
                                              int* __restrict__ gcur, int NBK) {
  __shared__ int part[BS];
  int C = (NBK + BS - 1) / BS;
  int s = 0;
  for (int k = 0; k < C; ++k) {
    int idx = threadIdx.x * C + k;
    if (idx < NBK) s += gh[idx];
  }
  part[threadIdx.x] = s;
  __syncthreads();
  for (int off = 1; off < BS; off <<= 1) {
    int v = part[threadIdx.x];
    int u = (threadIdx.x >= off) ? part[threadIdx.x - off] : 0;
    __syncthreads();
    part[threadIdx.x] = v + u;
    __syncthreads();
  }
  int run = (threadIdx.x > 0) ? part[threadIdx.x - 1] : 0;
  for (int k = 0; k < C; ++k) {
    int idx = threadIdx.x * C + k;
    if (idx < NBK) {
      gboff[idx] = run;
      gcur[idx] = run;
      run += gh[idx];
    }
  }
  if (threadIdx.x == BS - 1) gboff[NBK] = run;  // == total items
}

// node placement: single pass, deterministic cursors
__global__ __launch_bounds__(BS) void k_bplace(const int* __restrict__ ei,
                                               const int* __restrict__ gboff,
                                               const int* __restrict__ tbase,
                                               int2* __restrict__ P, int M, int NBK) {
  __shared__ int cur[NBK_MAX];
  int t = blockIdx.x;
  for (int b = threadIdx.x; b < NBK; b += BS)
    cur[b] = gboff[b] + tbase[t * NBK + b];
  __syncthreads();
  int e0 = t * EBT;
  int n = min(EBT, M - e0);
  for (int k = threadIdx.x; k < n; k += BS) {
    int sidx = ei[e0 + k];
    int d = ei[M + e0 + k];
    int pos = atomicAdd(&cur[d / NPB], 1);
    P[pos] = make_int2(sidx, d);
  }
}

// edge placement with VALUE carried: PEV = (key, val) -- runs after k_l2head,
// reads keys + dd sequentially; k_oecsum2 then has zero random transactions.
__global__ __launch_bounds__(BS) void k_escatv(const int* __restrict__ c12,
                                               const int* __restrict__ c13,
                                               const int* __restrict__ c23,
                                               const float* __restrict__ dd,
                                               const int* __restrict__ gboff,
                                               const int* __restrict__ tbase,
                                               int2* __restrict__ PEV, int T, int NBK) {
  __shared__ int cur[NBK_MAX];
  int t = blockIdx.x;
  for (int b = threadIdx.x; b < NBK; b += BS)
    cur[b] = gboff[b] + tbase[t * NBK + b];
  __syncthreads();
  int N3 = 3 * T;
  int j0 = t * EBT;
  int n = min(EBT, N3 - j0);
  for (int k = threadIdx.x; k < n; k += BS) {
    int j = j0 + k;
    int key = (j < T) ? c12[j] : ((j < 2 * T) ? c13[j - T] : c23[j - 2 * T]);
    float v = dd[j];
    int pos = atomicAdd(&cur[key / NPB_E], 1);
    PEV[pos] = make_int2(key, __builtin_bit_cast(int, v));
  }
}

// ---------------- pass D — per-bucket LDS counting sort -> row_ptr + srt ----------------

__global__ __launch_bounds__(BS) void k_bfinal(const int2* __restrict__ P,
                                               const int* __restrict__ gboff,
                                               int* __restrict__ row_ptr,
                                               int* __restrict__ srt, int T, int M,
                                               int NBK) {
  __shared__ int cnt[NPB];
  __shared__ int lsrt[CAP];
  __shared__ int part[BS];
  int b = blockIdx.x;
  int d0 = b * NPB;
  int nodesHere = min(NPB, T - d0);
  int p0 = gboff[b], p1 = gboff[b + 1];
  int nE = p1 - p0;
  for (int j = threadIdx.x; j < NPB; j += BS) cnt[j] = 0;
  __syncthreads();
  for (int j = threadIdx.x; j < nE; j += BS) {
    int2 p = P[p0 + j];
    atomicAdd(&cnt[p.y - d0], 1);
  }
  __syncthreads();
  const int CN = NPB / BS;  // 16
  int s = 0;
#pragma unroll
  for (int k = 0; k < CN; ++k) s += cnt[threadIdx.x * CN + k];
  part[threadIdx.x] = s;
  __syncthreads();
  for (int off = 1; off < BS; off <<= 1) {
    int v = part[threadIdx.x];
    int u = (threadIdx.x >= off) ? part[threadIdx.x - off] : 0;
    __syncthreads();
    part[threadIdx.x] = v + u;
    __syncthreads();
  }
  int run = (threadIdx.x > 0) ? part[threadIdx.x - 1] : 0;
#pragma unroll
  for (int k = 0; k < CN; ++k) {
    int idx = threadIdx.x * CN + k;
    int c = cnt[idx];
    cnt[idx] = run;
    if (idx < nodesHere) row_ptr[d0 + idx] = p0 + run;
    run += c;
  }
  if (b == NBK - 1 && threadIdx.x == 0) row_ptr[T] = M;
  __syncthreads();
  if (nE <= CAP) {
    for (int j = threadIdx.x; j < nE; j += BS) {
      int2 p = P[p0 + j];
      int pos = atomicAdd(&cnt[p.y - d0], 1);
      lsrt[pos] = p.x;
    }
    __syncthreads();
    for (int j = threadIdx.x; j < nE; j += BS) srt[p0 + j] = lsrt[j];
  } else {
    for (int j = threadIdx.x; j < nE; j += BS) {
      int2 p = P[p0 + j];
      int pos = atomicAdd(&cnt[p.y - d0], 1);
      srt[p0 + pos] = p.x;
    }
  }
}

// per-bucket reduce: oec[e] += sum of carried values; pure sequential reads.
__global__ __launch_bounds__(BS) void k_oecsum2(const int2* __restrict__ PEV,
                                                const int* __restrict__ gboff,
                                                float* __restrict__ oec, int E) {
  __shared__ float acc[NPB_E];
  int b = blockIdx.x;
  int e0 = b * NPB_E;
  int p0 = gboff[b], p1 = gboff[b + 1];
  int n = p1 - p0;
  for (int j = threadIdx.x; j < NPB_E; j += BS) acc[j] = 0.0f;
  __syncthreads();
  int k = threadIdx.x;
  for (; k + 3 * BS < n; k += 4 * BS) {
    int2 q0 = PEV[p0 + k];
    int2 q1 = PEV[p0 + k + BS];
    int2 q2 = PEV[p0 + k + 2 * BS];
    int2 q3 = PEV[p0 + k + 3 * BS];
    atomicAdd(&acc[q0.x - e0], __builtin_bit_cast(float, q0.y));
    atomicAdd(&acc[q1.x - e0], __builtin_bit_cast(float, q1.y));
    atomicAdd(&acc[q2.x - e0], __builtin_bit_cast(float, q2.y));
    atomicAdd(&acc[q3.x - e0], __builtin_bit_cast(float, q3.y));
  }
  for (; k < n; k += BS) {
    int2 q = PEV[p0 + k];
    atomicAdd(&acc[q.x - e0], __builtin_bit_cast(float, q.y));
  }
  __syncthreads();
  int lim = min(NPB_E, E - e0);
  for (int j = threadIdx.x; j < lim; j += BS) oec[e0 + j] += acc[j];
}

// ---------------- math kernels ----------------

// msg[e] = ec[e]/cnt[e]; oec[e] = (cnt>0) ? 0 : ec  (one pass over E)
__global__ void k_prep_e(const float* __restrict__ ec, const float* __restrict__ cnt,
                         float* __restrict__ msg, float* __restrict__ oec, int E) {
  int i = blockIdx.x * BS + threadIdx.x;
  if (i >= E) return;
  float c = cnt[i], v = ec[i];
  msg[i] = v / c;
  oec[i] = (c > 0.0f) ? 0.0f : v;
}

// step 1: tri4[i] = (t12+msg, t13+msg, t23+msg, dis_i)  (f32, for self/outputs)
//         trih[i] = same row packed half4 (8B, gather table for layer 1)
__global__ void k_step1pack(const float* __restrict__ msg,
                            const float* __restrict__ t12, const float* __restrict__ t13,
                            const float* __restrict__ t23,
                            const int* __restrict__ c12, const int* __restrict__ c13,
                            const int* __restrict__ c23,
                            const int* __restrict__ row_ptr,
                            float4* __restrict__ tri4, uint2* __restrict__ trih, int T) {
  int i = blockIdx.x * BS + threadIdx.x;
  if (i >= T) return;
  int a = c12[i], b = c13[i], c = c23[i];
  float4 v;
  v.x = t12[i] + msg[a];
  v.y = t13[i] + msg[b];
  v.z = t23[i] + msg[c];
  v.w = rsqrtf((float)(row_ptr[i + 1] - row_ptr[i]) + 1.0f);
  tri4[i] = v;
  uint2 h;
  h.x = pack2(v.x, v.y);
  h.y = pack2(v.z, v.w);
  trih[i] = h;
}

// ---- pack weights to half2 (one-time, trivially cheap) ----
__global__ void k_packw(const float* __restrict__ W1, const float* __restrict__ b1,
                        const float* __restrict__ W2, uint* __restrict__ pkw) {
  int i = blockIdx.x * BS + threadIdx.x;
  if (i < 48) {
    int r = i >> 4, k = i & 15;
    pkw[i] = pack2(W1[r * HID + 2 * k], W1[r * HID + 2 * k + 1]);
  } else if (i < 64) {
    int k = i - 48;
    pkw[i] = pack2(b1[2 * k], b1[2 * k + 1]);
  } else if (i < 576) {
    int idx = i - 64;
    int h2 = idx >> 5, j = idx & 31;
    pkw[i] = pack2(W2[(2 * h2) * HID + j], W2[(2 * h2 + 1) * HID + j]);
  }
}

// accumulate one gathered half4 tri row: (ax,ay,az) += tri.xyz * (tri.w * di)
__device__ __forceinline__ void acc3(uint2 g, float di, float& ax, float& ay, float& az) {
  h2v lo = u2h(g.x), hi = u2h(g.y);
  float w = (float)hi.y * di;
  ax = fmaf((float)lo.x, w, ax);
  ay = fmaf((float)lo.y, w, ay);
  az = fmaf((float)hi.x, w, az);
}

// ---- layer-1 aggregate (pre-W1, linearity) -> G4h = half4(ax,ay,az,di), 8B rows ----
__global__ __launch_bounds__(BS) void k_agg1c(const int* __restrict__ row_ptr,
                                              const int* __restrict__ srt,
                                              const float4* __restrict__ tri4,
                                              const uint2* __restrict__ trih,
                                              uint2* __restrict__ G4h, int T) {
  int i = blockIdx.x * BS + threadIdx.x;
  if (i >= T) return;
  int r0 = row_ptr[i], r1 = row_ptr[i + 1];
  float4 ts = tri4[i];
  float di = ts.w;
  float d2 = di * di;
  float ax = ts.x * d2, ay = ts.y * d2, az = ts.z * d2;
  int e = r0;
  for (; e + 4 <= r1; e += 4) {
    int s0 = srt[e + 0];
    int s1 = srt[e + 1];
    int s2 = srt[e + 2];
    int s3 = srt[e + 3];
    uint2 g0 = trih[s0];
    uint2 g1 = trih[s1];
    uint2 g2 = trih[s2];
    uint2 g3 = trih[s3];
    acc3(g0, di, ax, ay, az);
    acc3(g1, di, ax, ay, az);
    acc3(g2, di, ax, ay, az);
    acc3(g3, di, ax, ay, az);
  }
  for (; e < r1; ++e) {
    uint2 g = trih[srt[e]];
    acc3(g, di, ax, ay, az);
  }
  uint2 o;
  o.x = pack2(ax, ay);
  o.y = pack2(az, di);
  G4h[i] = o;
}

// per-edge packed h1 expand + f32 mix-accumulate from an 8B half4 G row:
// S[2k..] += relu((gx,gy,gz)@W1 + b1)[2k..] * w
__device__ __forceinline__ void edge_h1_accu(uint2 g, float w,
                                             const uint* __restrict__ W1s,
                                             const uint* __restrict__ b1s,
                                             float* S) {
  h2v lo = u2h(g.x), hi = u2h(g.y);
  h2v hx; hx.x = lo.x; hx.y = lo.x;
  h2v hy; hy.x = lo.y; hy.y = lo.y;
  h2v hz; hz.x = hi.x; hz.y = hi.x;
  h2v zero; zero.x = (_Float16)0.f; zero.y = (_Float16)0.f;
#pragma unroll
  for (int k = 0; k < 16; ++k) {
    h2v t = hx * u2h(W1s[k]) + (hy * u2h(W1s[16 + k]) + (hz * u2h(W1s[32 + k]) + u2h(b1s[k])));
    t = __builtin_elementwise_max(t, zero);
    S[2 * k]     = fmaf((float)t.x, w, S[2 * k]);
    S[2 * k + 1] = fmaf((float)t.y, w, S[2 * k + 1]);
  }
}

// fused layer-2 (recompute-h1 from 8B G4h gathers) + packed W2 + head.
// R7: 112us, VALU 80% -- healthy; unchanged this round.
__global__ __launch_bounds__(BS) void k_l2head(
    const int* __restrict__ row_ptr, const int* __restrict__ srt,
    const uint2* __restrict__ G4h, const float4* __restrict__ tri4,
    const uint* __restrict__ pkw,
    const float* __restrict__ b2,
    const float* __restrict__ Wout, const float* __restrict__ bout,
    float* __restrict__ o12, float* __restrict__ o13, float* __restrict__ o23,
    float* __restrict__ dd, int T) {
  int i = blockIdx.x * BS + threadIdx.x;
  if (i >= T) return;
  int r0 = row_ptr[i], r1 = row_ptr[i + 1];
  uint2 gs = G4h[i];
  float4 tp = tri4[i];
  float di = tp.w;
  const uint* W1s = pkw;        // 48 u32
  const uint* b1s = pkw + 48;   // 16 u32
  const uint* W2s = pkw + 64;   // 512 u32

  float S[HID];
#pragma unroll
  for (int h = 0; h < HID; ++h) S[h] = 0.0f;

  // self-loop term: h1(G_i) * di^2
  edge_h1_accu(gs, di * di, W1s, b1s, S);

  // edge terms: h1(G_src) * (d_src * d_i); 4/2/1 ladder keeps up to 4 random
  // 8B loads in flight before any h1 math.
  int e = r0;
  for (; e + 4 <= r1; e += 4) {
    int s0 = srt[e + 0];
    int s1 = srt[e + 1];
    int s2 = srt[e + 2];
    int s3 = srt[e + 3];
    uint2 g0 = G4h[s0];
    uint2 g1 = G4h[s1];
    uint2 g2 = G4h[s2];
    uint2 g3 = G4h[s3];
    float w0 = h4w(g0) * di;
    float w1 = h4w(g1) * di;
    float w2 = h4w(g2) * di;
    float w3 = h4w(g3) * di;
    edge_h1_accu(g0, w0, W1s, b1s, S);
    edge_h1_accu(g1, w1, W1s, b1s, S);
    edge_h1_accu(g2, w2, W1s, b1s, S);
    edge_h1_accu(g3, w3, W1s, b1s, S);
  }
  if (e + 2 <= r1) {
    int s0 = srt[e + 0];
    int s1 = srt[e + 1];
    uint2 g0 = G4h[s0];
    uint2 g1 = G4h[s1];
    float w0 = h4w(g0) * di;
    float w1 = h4w(g1) * di;
    edge_h1_accu(g0, w0, W1s, b1s, S);
    edge_h1_accu(g1, w1, W1s, b1s, S);
    e += 2;
  }
  if (e < r1) {
    uint2 g = G4h[srt[e]];
    edge_h1_accu(g, h4w(g) * di, W1s, b1s, S);
  }

  // pack S once into consecutive-h half2 pairs for dot2
  uint sh[16];
#pragma unroll
  for (int k = 0; k < 16; ++k) sh[k] = pack2(S[2 * k], S[2 * k + 1]);

  // z = S @ W2 + b2 via v_dot2_f32_f16 (f32 accumulate); head folded per chunk of 8
  float d0 = bout[0], d1 = bout[1], dd2 = bout[2];
#pragma unroll
  for (int cz = 0; cz < 4; ++cz) {
    float z[8];
#pragma unroll
    for (int j = 0; j < 8; ++j) z[j] = b2[cz * 8 + j];
#pragma unroll
    for (int h2 = 0; h2 < 16; ++h2) {
#pragma unroll
      for (int j = 0; j < 8; ++j)
        z[j] = dot2acc(sh[h2], W2s[h2 * HID + cz * 8 + j], z[j]);
    }
#pragma unroll
    for (int j = 0; j < 8; ++j) {
      float v = fmaxf(z[j], 0.0f);
      int jp = cz * 8 + j;
      d0  = fmaf(v, Wout[jp * 3 + 0], d0);
      d1  = fmaf(v, Wout[jp * 3 + 1], d1);
      dd2 = fmaf(v, Wout[jp * 3 + 2], dd2);
    }
  }

  o12[i] = tp.x - d0;
  o13[i] = tp.y - d1;
  o23[i] = tp.z - dd2;
  // coalesced delta streams, laid out so dd[j] matches contributor id j
  dd[i] = d0;
  dd[T + i] = d1;
  dd[2 * T + i] = dd2;
}

// ---------------- launch ----------------

extern "C" void kernel_launch(void* const* d_in, const int* in_sizes, int n_in,
                              void* d_out, int out_size, void* d_ws, size_t ws_size,
                              hipStream_t stream) {
  const float* ec  = (const float*)d_in[0];
  const float* t12 = (const float*)d_in[1];
  const float* t13 = (const float*)d_in[2];
  const float* t23 = (const float*)d_in[3];
  const int* c12   = (const int*)d_in[4];
  const int* c13   = (const int*)d_in[5];
  const int* c23   = (const int*)d_in[6];
  const float* cnt = (const float*)d_in[7];
  const int* ei    = (const int*)d_in[8];
  const float* W1  = (const float*)d_in[9];
  const float* b1  = (const float*)d_in[10];
  const float* W2  = (const float*)d_in[11];
  const float* b2  = (const float*)d_in[12];
  const float* Wout = (const float*)d_in[13];
  const float* bout = (const float*)d_in[14];

  const int E = in_sizes[0];
  const int T = in_sizes[1];
  const int M = in_sizes[8] / 2;
  const int NBK = (T + NPB - 1) / NPB;        // node buckets (489)
  const int NBK_E = (E + NPB_E - 1) / NPB_E;  // edge buckets (489)

  float* oec = (float*)d_out;
  float* o12 = oec + E;
  float* o13 = o12 + T;
  float* o23 = o13 + T;

  auto blocks = [](long n) { return (int)((n + BS - 1) / BS); };
  const int tiles   = (M + EBT - 1) / EBT;          // 489
  const int tiles_e = (3 * T + EBT - 1) / EBT;      // 733

  // workspace (~176 MB):
  // tri4 32MB | trih 16 | G4h 16 | PEV 48 (int2*3T) | dd 24 | srt 16 | rptr 8 |
  // msg 4 | gboff/gcur/gh | pkw | gh_e/gboff_e/gcur_e | thist_n/tbase_n (~1MB ea) |
  // thist_e/tbase_e (~1.4MB ea)
  // P (int2*M = 32MB) aliases tri4 (P dead after k_bfinal; tri4 written in k_step1pack).
  float4* tri4 = (float4*)d_ws;
  uint2*  trih = (uint2*)(tri4 + T);
  uint2*  G4h  = trih + T;
  int2*   PEV  = (int2*)(G4h + T);            // 3T pairs
  float*  dd   = (float*)(PEV + 3 * (size_t)T);
  int*    srt  = (int*)(dd + 3 * (size_t)T);
  int*    rptr = srt + M;
  float*  msg  = (float*)(rptr + (T + 1));
  int*    gh   = (int*)(msg + E);
  int*    gboff = gh + NBK;
  int*    gcur  = gboff + (NBK + 1);
  uint*   pkw   = (uint*)(gcur + NBK);
  int*    gh_e  = (int*)(pkw + 576);
  int*    gboff_e = gh_e + NBK_E;
  int*    gcur_e  = gboff_e + (NBK_E + 1);
  int*    thist_n = gcur_e + NBK_E;
  int*    tbase_n = thist_n + (size_t)tiles * NBK;
  int*    thist_e = tbase_n + (size_t)tiles * NBK;
  int*    tbase_e = thist_e + (size_t)tiles_e * NBK_E;
  int2*   P    = (int2*)tri4;  // alias: dead before tri4 written

  // node sort: hist (persist per-tile) -> tile scan -> bucket scan -> place -> final
  k_bhist2<<<tiles, BS, 0, stream>>>(ei, thist_n, M, NBK);
  k_tbase<<<NBK, BS, 0, stream>>>(thist_n, tbase_n, gh, NBK, tiles);
  k_bscan<<<1, BS, 0, stream>>>(gh, gboff, gcur, NBK);
  k_bplace<<<tiles, BS, 0, stream>>>(ei, gboff, tbase_n, P, M, NBK);
  k_bfinal<<<NBK, BS, 0, stream>>>(P, gboff, rptr, srt, T, M, NBK);

  // edge-inverse bucketing (index-only prep; value scatter runs after l2head)
  k_ehist2<<<tiles_e, BS, 0, stream>>>(c12, c13, c23, thist_e, T, NBK_E);
  k_tbase<<<NBK_E, BS, 0, stream>>>(thist_e, tbase_e, gh_e, NBK_E, tiles_e);
  k_bscan<<<1, BS, 0, stream>>>(gh_e, gboff_e, gcur_e, NBK_E);

  // pack weights (tiny), per-edge prep, step-1 pack (f32 + half4 copies)
  k_packw<<<3, BS, 0, stream>>>(W1, b1, W2, pkw);
  k_prep_e<<<blocks(E), BS, 0, stream>>>(ec, cnt, msg, oec, E);
  k_step1pack<<<blocks(T), BS, 0, stream>>>(msg, t12, t13, t23, c12, c13, c23,
                                            rptr, tri4, trih, T);

  // layer 1 aggregate (pre-W1) -> half4 G rows
  k_agg1c<<<blocks(T), BS, 0, stream>>>(rptr, srt, tri4, trih, G4h, T);

  // layer 2: gather 8B G rows, packed-f16 h1 recompute + dot2 W2 + head
  k_l2head<<<blocks(T), BS, 0, stream>>>(rptr, srt, G4h, tri4, pkw,
                                         b2, Wout, bout,
                                         o12, o13, o23, dd, T);

  // oec accumulation: value-carrying scatter (sequential reads) + bucket reduce
  k_escatv<<<tiles_e, BS, 0, stream>>>(c12, c13, c23, dd, gboff_e, tbase_e,
                                       PEV, T, NBK_E);
  k_oecsum2<<<NBK_E, BS, 0, stream>>>(PEV, gboff_e, oec, E);
}

// Round 9
// 594.834 us; speedup vs baseline: 1.2078x; 1.0394x over previous
//
#include <hip/hip_runtime.h>
#include <hip/hip_fp16.h>
#include <math.h>

#define HID 32
#define BS 256

// ---- bucketed counting-sort parameters (node sort, dst-keyed) ----
#define NPB 2048          // nodes per bucket (power of 2; dstLocal fits 11 bits)
#define NBK_MAX 1024      // LDS sizing cap for bucket count (T/NPB = 1024 exactly)
#define EBT 8192          // items per tile
#define CAP 6912          // per-bucket LDS srt capacity (mean 4096, +44 sigma)

// ---- edge-inverse bucketing (oec accumulation) ----
#define NPB_E 2048        // edges per bucket (key range per bucket)

// ---- packed half2 helpers (pure clang vector ops -> v_pk_* / v_dot2) ----
typedef _Float16 h2v __attribute__((ext_vector_type(2)));

__device__ __forceinline__ h2v u2h(uint u) { return __builtin_bit_cast(h2v, u); }
__device__ __forceinline__ uint h2u(h2v h) { return __builtin_bit_cast(uint, h); }
__device__ __forceinline__ uint pack2(float a, float b) {
  h2v r; r.x = (_Float16)a; r.y = (_Float16)b; return h2u(r);
}
// z += dot(half2 a, half2 b) with f32 accumulate (v_dot2_f32_f16)
__device__ __forceinline__ float dot2acc(uint a, uint b, float c) {
#if __has_builtin(__builtin_amdgcn_fdot2)
  return __builtin_amdgcn_fdot2(u2h(a), u2h(b), c, false);
#else
  h2v ah = u2h(a), bh = u2h(b);
  c = fmaf((float)ah.x, (float)bh.x, c);
  return fmaf((float)ah.y, (float)bh.y, c);
#endif
}
// extract the .w half (dis) of an 8B half4 row
__device__ __forceinline__ float h4w(uint2 g) {
  h2v hi = u2h(g.y); return (float)hi.y;
}

// ---------------- deterministic-tiling bucket machinery ----------------
// R8: deterministic tiling (persisted per-tile hists + tile-base scan) -100us.
// R9: byte-diet -- node pairs packed to 4B ((dstLocal<<21)|src, NPB=2048),
// f32 tri4 dropped (trih fp16 is the only triplet array), P aliases PEV.

// node-key histogram: per tile, write thist row (coalesced)
__global__ __launch_bounds__(BS) void k_bhist2(const int* __restrict__ ei,
                                               int* __restrict__ thist, int M, int NBK) {
  __shared__ int hist[NBK_MAX];
  for (int b = threadIdx.x; b < NBK; b += BS) hist[b] = 0;
  __syncthreads();
  int e0 = blockIdx.x * EBT;
  int n = min(EBT, M - e0);
  for (int k = threadIdx.x; k < n; k += BS) {
    int d = ei[M + e0 + k];
    atomicAdd(&hist[d / NPB], 1);
  }
  __syncthreads();
  for (int b = threadIdx.x; b < NBK; b += BS)
    thist[blockIdx.x * NBK + b] = hist[b];
}

// edge-key histogram over contributors j in [0,3T)
__global__ __launch_bounds__(BS) void k_ehist2(const int* __restrict__ c12,
                                               const int* __restrict__ c13,
                                               const int* __restrict__ c23,
                                               int* __restrict__ thist, int T, int NBK) {
  __shared__ int hist[NBK_MAX];
  for (int b = threadIdx.x; b < NBK; b += BS) hist[b] = 0;
  __syncthreads();
  int N3 = 3 * T;
  int j0 = blockIdx.x * EBT;
  int n = min(EBT, N3 - j0);
  for (int k = threadIdx.x; k < n; k += BS) {
    int j = j0 + k;
    int key = (j < T) ? c12[j] : ((j < 2 * T) ? c13[j - T] : c23[j - 2 * T]);
    atomicAdd(&hist[key / NPB_E], 1);
  }
  __syncthreads();
  for (int b = threadIdx.x; b < NBK; b += BS)
    thist[blockIdx.x * NBK + b] = hist[b];
}

// per-bucket exclusive scan over tiles: tbase[t][b], gh[b]=total
__global__ __launch_bounds__(BS) void k_tbase(const int* __restrict__ thist,
                                              int* __restrict__ tbase,
                                              int* __restrict__ gh, int NBK, int NT) {
  __shared__ int part[BS];
  int b = blockIdx.x;
  int C = (NT + BS - 1) / BS;
  int s = 0;
  for (int k = 0; k < C; ++k) {
    int t = threadIdx.x * C + k;
    if (t < NT) s += thist[t * NBK + b];
  }
  part[threadIdx.x] = s;
  __syncthreads();
  for (int off = 1; off < BS; off <<= 1) {
    int v = part[threadIdx.x];
    int u = (threadIdx.x >= off) ? part[threadIdx.x - off] : 0;
    __syncthreads();
    part[threadIdx.x] = v + u;
    __syncthreads();
  }
  int run = (threadIdx.x > 0) ? part[threadIdx.x - 1] : 0;
  for (int k = 0; k < C; ++k) {
    int t = threadIdx.x * C + k;
    if (t < NT) {
      int v = thist[t * NBK + b];
      tbase[t * NBK + b] = run;
      run += v;
    }
  }
  if (threadIdx.x == BS - 1) gh[b] = run;
}

// single-block scan of bucket totals -> gboff (gcur scratch, unused downstream)
__global__ __launch_bounds__(BS) void k_bscan(const int* __restrict__ gh,
                                              int* __restrict__ gboff,
                                              int* __restrict__ gcur, int NBK) {
  __shared__ int part[BS];
  int C = (NBK + BS - 1) / BS;
  int s = 0;
  for (int k = 0; k < C; ++k) {
    int idx = threadIdx.x * C + k;
    if (idx < NBK) s += gh[idx];
  }
  part[threadIdx.x] = s;
  __syncthreads();
  for (int off = 1; off < BS; off <<= 1) {
    int v = part[threadIdx.x];
    int u = (threadIdx.x >= off) ? part[threadIdx.x - off] : 0;
    __syncthreads();
    part[threadIdx.x] = v + u;
    __syncthreads();
  }
  int run = (threadIdx.x > 0) ? part[threadIdx.x - 1] : 0;
  for (int k = 0; k < C; ++k) {
    int idx = threadIdx.x * C + k;
    if (idx < NBK) {
      gboff[idx] = run;
      gcur[idx] = run;
      run += gh[idx];
    }
  }
  if (threadIdx.x == BS - 1) gboff[NBK] = run;  // == total items
}

// node placement: single pass, deterministic cursors; 4B packed pairs
__global__ __launch_bounds__(BS) void k_bplace(const int* __restrict__ ei,
                                               const int* __restrict__ gboff,
                                               const int* __restrict__ tbase,
                                               uint* __restrict__ P, int M, int NBK) {
  __shared__ int cur[NBK_MAX];
  int t = blockIdx.x;
  for (int b = threadIdx.x; b < NBK; b += BS)
    cur[b] = gboff[b] + tbase[t * NBK + b];
  __syncthreads();
  int e0 = t * EBT;
  int n = min(EBT, M - e0);
  for (int k = threadIdx.x; k < n; k += BS) {
    uint sidx = (uint)ei[e0 + k];
    int d = ei[M + e0 + k];
    int pos = atomicAdd(&cur[d / NPB], 1);
    P[pos] = ((uint)(d & (NPB - 1)) << 21) | sidx;   // src < 2^21 (T = 2M)
  }
}

// edge placement with VALUE carried: PEV = (key, f32 val) -- runs after k_l2head,
// reads keys + dd sequentially; k_oecsum2 then has zero random transactions.
__global__ __launch_bounds__(BS) void k_escatv(const int* __restrict__ c12,
                                               const int* __restrict__ c13,
                                               const int* __restrict__ c23,
                                               const float* __restrict__ dd,
                                               const int* __restrict__ gboff,
                                               const int* __restrict__ tbase,
                                               int2* __restrict__ PEV, int T, int NBK) {
  __shared__ int cur[NBK_MAX];
  int t = blockIdx.x;
  for (int b = threadIdx.x; b < NBK; b += BS)
    cur[b] = gboff[b] + tbase[t * NBK + b];
  __syncthreads();
  int N3 = 3 * T;
  int j0 = t * EBT;
  int n = min(EBT, N3 - j0);
  for (int k = threadIdx.x; k < n; k += BS) {
    int j = j0 + k;
    int key = (j < T) ? c12[j] : ((j < 2 * T) ? c13[j - T] : c23[j - 2 * T]);
    float v = dd[j];
    int pos = atomicAdd(&cur[key / NPB_E], 1);
    PEV[pos] = make_int2(key, __builtin_bit_cast(int, v));
  }
}

// ---------------- pass D — per-bucket LDS counting sort -> row_ptr + srt ----------------
// 4B packed pairs; LDS now ~37KB -> 2 blocks/CU (was 64KB -> 1).

__global__ __launch_bounds__(BS) void k_bfinal(const uint* __restrict__ P,
                                               const int* __restrict__ gboff,
                                               int* __restrict__ row_ptr,
                                               int* __restrict__ srt, int T, int M,
                                               int NBK) {
  __shared__ int cnt[NPB];
  __shared__ int lsrt[CAP];
  __shared__ int part[BS];
  int b = blockIdx.x;
  int d0 = b * NPB;
  int nodesHere = min(NPB, T - d0);
  int p0 = gboff[b], p1 = gboff[b + 1];
  int nE = p1 - p0;
  for (int j = threadIdx.x; j < NPB; j += BS) cnt[j] = 0;
  __syncthreads();
  for (int j = threadIdx.x; j < nE; j += BS) {
    uint p = P[p0 + j];
    atomicAdd(&cnt[p >> 21], 1);
  }
  __syncthreads();
  const int CN = NPB / BS;  // 8
  int s = 0;
#pragma unroll
  for (int k = 0; k < CN; ++k) s += cnt[threadIdx.x * CN + k];
  part[threadIdx.x] = s;
  __syncthreads();
  for (int off = 1; off < BS; off <<= 1) {
    int v = part[threadIdx.x];
    int u = (threadIdx.x >= off) ? part[threadIdx.x - off] : 0;
    __syncthreads();
    part[threadIdx.x] = v + u;
    __syncthreads();
  }
  int run = (threadIdx.x > 0) ? part[threadIdx.x - 1] : 0;
#pragma unroll
  for (int k = 0; k < CN; ++k) {
    int idx = threadIdx.x * CN + k;
    int c = cnt[idx];
    cnt[idx] = run;
    if (idx < nodesHere) row_ptr[d0 + idx] = p0 + run;
    run += c;
  }
  if (b == NBK - 1 && threadIdx.x == 0) row_ptr[T] = M;
  __syncthreads();
  if (nE <= CAP) {
    for (int j = threadIdx.x; j < nE; j += BS) {
      uint p = P[p0 + j];
      int pos = atomicAdd(&cnt[p >> 21], 1);
      lsrt[pos] = (int)(p & 0x1FFFFFu);
    }
    __syncthreads();
    for (int j = threadIdx.x; j < nE; j += BS) srt[p0 + j] = lsrt[j];
  } else {  // overflow fallback (statistically unreachable)
    for (int j = threadIdx.x; j < nE; j += BS) {
      uint p = P[p0 + j];
      int pos = atomicAdd(&cnt[p >> 21], 1);
      srt[p0 + pos] = (int)(p & 0x1FFFFFu);
    }
  }
}

// per-bucket reduce: oec[e] += sum of carried values; pure sequential reads.
__global__ __launch_bounds__(BS) void k_oecsum2(const int2* __restrict__ PEV,
                                                const int* __restrict__ gboff,
                                                float* __restrict__ oec, int E) {
  __shared__ float acc[NPB_E];
  int b = blockIdx.x;
  int e0 = b * NPB_E;
  int p0 = gboff[b], p1 = gboff[b + 1];
  int n = p1 - p0;
  for (int j = threadIdx.x; j < NPB_E; j += BS) acc[j] = 0.0f;
  __syncthreads();
  int k = threadIdx.x;
  for (; k + 3 * BS < n; k += 4 * BS) {
    int2 q0 = PEV[p0 + k];
    int2 q1 = PEV[p0 + k + BS];
    int2 q2 = PEV[p0 + k + 2 * BS];
    int2 q3 = PEV[p0 + k + 3 * BS];
    atomicAdd(&acc[q0.x - e0], __builtin_bit_cast(float, q0.y));
    atomicAdd(&acc[q1.x - e0], __builtin_bit_cast(float, q1.y));
    atomicAdd(&acc[q2.x - e0], __builtin_bit_cast(float, q2.y));
    atomicAdd(&acc[q3.x - e0], __builtin_bit_cast(float, q3.y));
  }
  for (; k < n; k += BS) {
    int2 q = PEV[p0 + k];
    atomicAdd(&acc[q.x - e0], __builtin_bit_cast(float, q.y));
  }
  __syncthreads();
  int lim = min(NPB_E, E - e0);
  for (int j = threadIdx.x; j < lim; j += BS) oec[e0 + j] += acc[j];
}

// ---------------- math kernels ----------------

// msg[e] = ec[e]/cnt[e]; oec[e] = (cnt>0) ? 0 : ec  (one pass over E)
__global__ void k_prep_e(const float* __restrict__ ec, const float* __restrict__ cnt,
                         float* __restrict__ msg, float* __restrict__ oec, int E) {
  int i = blockIdx.x * BS + threadIdx.x;
  if (i >= E) return;
  float c = cnt[i], v = ec[i];
  msg[i] = v / c;
  oec[i] = (c > 0.0f) ? 0.0f : v;
}

// step 1: trih[i] = half4(t12+msg, t13+msg, t23+msg, dis_i)  (fp16, 8B rows)
// f32 tri4 dropped (R9): outputs reconstruct t from trih; |t|<~6 -> fp16 err <=4e-3.
__global__ void k_step1pack(const float* __restrict__ msg,
                            const float* __restrict__ t12, const float* __restrict__ t13,
                            const float* __restrict__ t23,
                            const int* __restrict__ c12, const int* __restrict__ c13,
                            const int* __restrict__ c23,
                            const int* __restrict__ row_ptr,
                            uint2* __restrict__ trih, int T) {
  int i = blockIdx.x * BS + threadIdx.x;
  if (i >= T) return;
  int a = c12[i], b = c13[i], c = c23[i];
  float vx = t12[i] + msg[a];
  float vy = t13[i] + msg[b];
  float vz = t23[i] + msg[c];
  float vw = rsqrtf((float)(row_ptr[i + 1] - row_ptr[i]) + 1.0f);
  uint2 h;
  h.x = pack2(vx, vy);
  h.y = pack2(vz, vw);
  trih[i] = h;
}

// ---- pack weights to half2 (one-time, trivially cheap) ----
__global__ void k_packw(const float* __restrict__ W1, const float* __restrict__ b1,
                        const float* __restrict__ W2, uint* __restrict__ pkw) {
  int i = blockIdx.x * BS + threadIdx.x;
  if (i < 48) {
    int r = i >> 4, k = i & 15;
    pkw[i] = pack2(W1[r * HID + 2 * k], W1[r * HID + 2 * k + 1]);
  } else if (i < 64) {
    int k = i - 48;
    pkw[i] = pack2(b1[2 * k], b1[2 * k + 1]);
  } else if (i < 576) {
    int idx = i - 64;
    int h2 = idx >> 5, j = idx & 31;
    pkw[i] = pack2(W2[(2 * h2) * HID + j], W2[(2 * h2 + 1) * HID + j]);
  }
}

// accumulate one gathered half4 tri row: (ax,ay,az) += tri.xyz * (tri.w * di)
__device__ __forceinline__ void acc3(uint2 g, float di, float& ax, float& ay, float& az) {
  h2v lo = u2h(g.x), hi = u2h(g.y);
  float w = (float)hi.y * di;
  ax = fmaf((float)lo.x, w, ax);
  ay = fmaf((float)lo.y, w, ay);
  az = fmaf((float)hi.x, w, az);
}

// ---- layer-1 aggregate (pre-W1, linearity) -> G4h = half4(ax,ay,az,di), 8B rows ----
__global__ __launch_bounds__(BS) void k_agg1c(const int* __restrict__ row_ptr,
                                              const int* __restrict__ srt,
                                              const uint2* __restrict__ trih,
                                              uint2* __restrict__ G4h, int T) {
  int i = blockIdx.x * BS + threadIdx.x;
  if (i >= T) return;
  int r0 = row_ptr[i], r1 = row_ptr[i + 1];
  uint2 ts = trih[i];
  h2v tlo = u2h(ts.x), thi = u2h(ts.y);
  float di = (float)thi.y;
  float d2 = di * di;
  float ax = (float)tlo.x * d2, ay = (float)tlo.y * d2, az = (float)thi.x * d2;
  int e = r0;
  for (; e + 4 <= r1; e += 4) {
    int s0 = srt[e + 0];
    int s1 = srt[e + 1];
    int s2 = srt[e + 2];
    int s3 = srt[e + 3];
    uint2 g0 = trih[s0];
    uint2 g1 = trih[s1];
    uint2 g2 = trih[s2];
    uint2 g3 = trih[s3];
    acc3(g0, di, ax, ay, az);
    acc3(g1, di, ax, ay, az);
    acc3(g2, di, ax, ay, az);
    acc3(g3, di, ax, ay, az);
  }
  for (; e < r1; ++e) {
    uint2 g = trih[srt[e]];
    acc3(g, di, ax, ay, az);
  }
  uint2 o;
  o.x = pack2(ax, ay);
  o.y = pack2(az, di);
  G4h[i] = o;
}

// per-edge packed h1 expand + f32 mix-accumulate from an 8B half4 G row:
// S[2k..] += relu((gx,gy,gz)@W1 + b1)[2k..] * w
__device__ __forceinline__ void edge_h1_accu(uint2 g, float w,
                                             const uint* __restrict__ W1s,
                                             const uint* __restrict__ b1s,
                                             float* S) {
  h2v lo = u2h(g.x), hi = u2h(g.y);
  h2v hx; hx.x = lo.x; hx.y = lo.x;
  h2v hy; hy.x = lo.y; hy.y = lo.y;
  h2v hz; hz.x = hi.x; hz.y = hi.x;
  h2v zero; zero.x = (_Float16)0.f; zero.y = (_Float16)0.f;
#pragma unroll
  for (int k = 0; k < 16; ++k) {
    h2v t = hx * u2h(W1s[k]) + (hy * u2h(W1s[16 + k]) + (hz * u2h(W1s[32 + k]) + u2h(b1s[k])));
    t = __builtin_elementwise_max(t, zero);
    S[2 * k]     = fmaf((float)t.x, w, S[2 * k]);
    S[2 * k + 1] = fmaf((float)t.y, w, S[2 * k + 1]);
  }
}

// fused layer-2 (recompute-h1 from 8B G4h gathers) + packed W2 + head.
// R7/R8: 113us, VALU ~80% -- healthy. R9: reads trih[i] (8B) instead of f32 tri4.
__global__ __launch_bounds__(BS) void k_l2head(
    const int* __restrict__ row_ptr, const int* __restrict__ srt,
    const uint2* __restrict__ G4h, const uint2* __restrict__ trih,
    const uint* __restrict__ pkw,
    const float* __restrict__ b2,
    const float* __restrict__ Wout, const float* __restrict__ bout,
    float* __restrict__ o12, float* __restrict__ o13, float* __restrict__ o23,
    float* __restrict__ dd, int T) {
  int i = blockIdx.x * BS + threadIdx.x;
  if (i >= T) return;
  int r0 = row_ptr[i], r1 = row_ptr[i + 1];
  uint2 gs = G4h[i];
  uint2 tp = trih[i];
  h2v tlo = u2h(tp.x), thi = u2h(tp.y);
  float di = (float)thi.y;
  const uint* W1s = pkw;        // 48 u32
  const uint* b1s = pkw + 48;   // 16 u32
  const uint* W2s = pkw + 64;   // 512 u32

  float S[HID];
#pragma unroll
  for (int h = 0; h < HID; ++h) S[h] = 0.0f;

  // self-loop term: h1(G_i) * di^2
  edge_h1_accu(gs, di * di, W1s, b1s, S);

  // edge terms: h1(G_src) * (d_src * d_i); 4/2/1 ladder keeps up to 4 random
  // 8B loads in flight before any h1 math.
  int e = r0;
  for (; e + 4 <= r1; e += 4) {
    int s0 = srt[e + 0];
    int s1 = srt[e + 1];
    int s2 = srt[e + 2];
    int s3 = srt[e + 3];
    uint2 g0 = G4h[s0];
    uint2 g1 = G4h[s1];
    uint2 g2 = G4h[s2];
    uint2 g3 = G4h[s3];
    float w0 = h4w(g0) * di;
    float w1 = h4w(g1) * di;
    float w2 = h4w(g2) * di;
    float w3 = h4w(g3) * di;
    edge_h1_accu(g0, w0, W1s, b1s, S);
    edge_h1_accu(g1, w1, W1s, b1s, S);
    edge_h1_accu(g2, w2, W1s, b1s, S);
    edge_h1_accu(g3, w3, W1s, b1s, S);
  }
  if (e + 2 <= r1) {
    int s0 = srt[e + 0];
    int s1 = srt[e + 1];
    uint2 g0 = G4h[s0];
    uint2 g1 = G4h[s1];
    float w0 = h4w(g0) * di;
    float w1 = h4w(g1) * di;
    edge_h1_accu(g0, w0, W1s, b1s, S);
    edge_h1_accu(g1, w1, W1s, b1s, S);
    e += 2;
  }
  if (e < r1) {
    uint2 g = G4h[srt[e]];
    edge_h1_accu(g, h4w(g) * di, W1s, b1s, S);
  }

  // pack S once into consecutive-h half2 pairs for dot2
  uint sh[16];
#pragma unroll
  for (int k = 0; k < 16; ++k) sh[k] = pack2(S[2 * k], S[2 * k + 1]);

  // z = S @ W2 + b2 via v_dot2_f32_f16 (f32 accumulate); head folded per chunk of 8
  float d0 = bout[0], d1 = bout[1], dd2 = bout[2];
#pragma unroll
  for (int cz = 0; cz < 4; ++cz) {
    float z[8];
#pragma unroll
    for (int j = 0; j < 8; ++j) z[j] = b2[cz * 8 + j];
#pragma unroll
    for (int h2 = 0; h2 < 16; ++h2) {
#pragma unroll
      for (int j = 0; j < 8; ++j)
        z[j] = dot2acc(sh[h2], W2s[h2 * HID + cz * 8 + j], z[j]);
    }
#pragma unroll
    for (int j = 0; j < 8; ++j) {
      float v = fmaxf(z[j], 0.0f);
      int jp = cz * 8 + j;
      d0  = fmaf(v, Wout[jp * 3 + 0], d0);
      d1  = fmaf(v, Wout[jp * 3 + 1], d1);
      dd2 = fmaf(v, Wout[jp * 3 + 2], dd2);
    }
  }

  o12[i] = (float)tlo.x - d0;
  o13[i] = (float)tlo.y - d1;
  o23[i] = (float)thi.x - dd2;
  // coalesced delta streams, laid out so dd[j] matches contributor id j
  dd[i] = d0;
  dd[T + i] = d1;
  dd[2 * T + i] = dd2;
}

// ---------------- launch ----------------

extern "C" void kernel_launch(void* const* d_in, const int* in_sizes, int n_in,
                              void* d_out, int out_size, void* d_ws, size_t ws_size,
                              hipStream_t stream) {
  const float* ec  = (const float*)d_in[0];
  const float* t12 = (const float*)d_in[1];
  const float* t13 = (const float*)d_in[2];
  const float* t23 = (const float*)d_in[3];
  const int* c12   = (const int*)d_in[4];
  const int* c13   = (const int*)d_in[5];
  const int* c23   = (const int*)d_in[6];
  const float* cnt = (const float*)d_in[7];
  const int* ei    = (const int*)d_in[8];
  const float* W1  = (const float*)d_in[9];
  const float* b1  = (const float*)d_in[10];
  const float* W2  = (const float*)d_in[11];
  const float* b2  = (const float*)d_in[12];
  const float* Wout = (const float*)d_in[13];
  const float* bout = (const float*)d_in[14];

  const int E = in_sizes[0];
  const int T = in_sizes[1];
  const int M = in_sizes[8] / 2;
  const int NBK = (T + NPB - 1) / NPB;        // node buckets (1024)
  const int NBK_E = (E + NPB_E - 1) / NPB_E;  // edge buckets (489)

  float* oec = (float*)d_out;
  float* o12 = oec + E;
  float* o13 = o12 + T;
  float* o23 = o13 + T;

  auto blocks = [](long n) { return (int)((n + BS - 1) / BS); };
  const int tiles   = (M + EBT - 1) / EBT;          // 489
  const int tiles_e = (3 * T + EBT - 1) / EBT;      // 733

  // workspace (~140 MB):
  // trih 16MB | G4h 16 | PEV 48 (int2*3T) | dd 24 | srt 16 | rptr 8 | msg 4 |
  // gh/gboff/gcur | pkw | gh_e/gboff_e/gcur_e | thist_n/tbase_n 2MB ea |
  // thist_e/tbase_e 1.4MB ea
  // P (uint*M = 16MB) aliases PEV (P dead after k_bfinal; PEV written by k_escatv).
  uint2*  trih = (uint2*)d_ws;
  uint2*  G4h  = trih + T;
  int2*   PEV  = (int2*)(G4h + T);            // 3T pairs
  float*  dd   = (float*)(PEV + 3 * (size_t)T);
  int*    srt  = (int*)(dd + 3 * (size_t)T);
  int*    rptr = srt + M;
  float*  msg  = (float*)(rptr + (T + 1));
  int*    gh   = (int*)(msg + E);
  int*    gboff = gh + NBK;
  int*    gcur  = gboff + (NBK + 1);
  uint*   pkw   = (uint*)(gcur + NBK);
  int*    gh_e  = (int*)(pkw + 576);
  int*    gboff_e = gh_e + NBK_E;
  int*    gcur_e  = gboff_e + (NBK_E + 1);
  int*    thist_n = gcur_e + NBK_E;
  int*    tbase_n = thist_n + (size_t)tiles * NBK;
  int*    thist_e = tbase_n + (size_t)tiles * NBK;
  int*    tbase_e = thist_e + (size_t)tiles_e * NBK_E;
  uint*   P    = (uint*)PEV;  // alias: dead before PEV written

  // node sort: hist (persist per-tile) -> tile scan -> bucket scan -> place -> final
  k_bhist2<<<tiles, BS, 0, stream>>>(ei, thist_n, M, NBK);
  k_tbase<<<NBK, BS, 0, stream>>>(thist_n, tbase_n, gh, NBK, tiles);
  k_bscan<<<1, BS, 0, stream>>>(gh, gboff, gcur, NBK);
  k_bplace<<<tiles, BS, 0, stream>>>(ei, gboff, tbase_n, P, M, NBK);
  k_bfinal<<<NBK, BS, 0, stream>>>(P, gboff, rptr, srt, T, M, NBK);

  // edge-inverse bucketing (index-only prep; value scatter runs after l2head)
  k_ehist2<<<tiles_e, BS, 0, stream>>>(c12, c13, c23, thist_e, T, NBK_E);
  k_tbase<<<NBK_E, BS, 0, stream>>>(thist_e, tbase_e, gh_e, NBK_E, tiles_e);
  k_bscan<<<1, BS, 0, stream>>>(gh_e, gboff_e, gcur_e, NBK_E);

  // pack weights (tiny), per-edge prep, step-1 pack (fp16 rows only)
  k_packw<<<3, BS, 0, stream>>>(W1, b1, W2, pkw);
  k_prep_e<<<blocks(E), BS, 0, stream>>>(ec, cnt, msg, oec, E);
  k_step1pack<<<blocks(T), BS, 0, stream>>>(msg, t12, t13, t23, c12, c13, c23,
                                            rptr, trih, T);

  // layer 1 aggregate (pre-W1) -> half4 G rows
  k_agg1c<<<blocks(T), BS, 0, stream>>>(rptr, srt, trih, G4h, T);

  // layer 2: gather 8B G rows, packed-f16 h1 recompute + dot2 W2 + head
  k_l2head<<<blocks(T), BS, 0, stream>>>(rptr, srt, G4h, trih, pkw,
                                         b2, Wout, bout,
                                         o12, o13, o23, dd, T);

  // oec accumulation: value-carrying scatter (sequential reads) + bucket reduce
  k_escatv<<<tiles_e, BS, 0, stream>>>(c12, c13, c23, dd, gboff_e, tbase_e,
                                       PEV, T, NBK_E);
  k_oecsum2<<<NBK_E, BS, 0, stream>>>(PEV, gboff_e, oec, E);
}